// Round 5
// baseline (27203.287 us; speedup 1.0000x reference)
//
#include <hip/hip_runtime.h>
#include <stdint.h>

#define B_  64
#define T_  2048
#define I_  256
#define H_  512
#define NG  4      // batch groups (16 batch each)
#define NP  8      // WGs per group, each owns HS h-elements
#define HS  64
#define NBLK 256

typedef __attribute__((ext_vector_type(8))) short  short8;
typedef __attribute__((ext_vector_type(4))) int    intx4;
typedef __attribute__((ext_vector_type(4))) float  floatx4;
typedef unsigned long long u64;

__device__ __forceinline__ unsigned short f2bf(float f) {
    unsigned u = __float_as_uint(f);
    u = (u + 0x7fffu + ((u >> 16) & 1u)) >> 16;   // RNE
    return (unsigned short)u;
}

__device__ __forceinline__ short8 ld8_bf(const float* p) {
    floatx4 a = *(const floatx4*)p;
    floatx4 c = *(const floatx4*)(p + 4);
    short8 r;
    r[0] = (short)f2bf(a[0]); r[1] = (short)f2bf(a[1]);
    r[2] = (short)f2bf(a[2]); r[3] = (short)f2bf(a[3]);
    r[4] = (short)f2bf(c[0]); r[5] = (short)f2bf(c[1]);
    r[6] = (short)f2bf(c[2]); r[7] = (short)f2bf(c[3]);
    return r;
}

__device__ __forceinline__ short8 as_s8(intx4 v) {
    union { intx4 i; short8 s; } u; u.i = v; return u.s;
}

__device__ __forceinline__ float sigf(float x) { return 1.f / (1.f + __expf(-x)); }
__device__ __forceinline__ float tanh_(float x) { return 2.f * sigf(2.f * x) - 1.f; }

// ---- L2-scope (same-XCD) primitives: sc0 = bypass L1, served by XCD L2 ----
__device__ __forceinline__ unsigned ld_ctr_l2(const unsigned* p) {
    unsigned v;
    asm volatile("global_load_dword %0, %1, off sc0\n\ts_waitcnt vmcnt(0)"
                 : "=&v"(v) : "v"(p) : "memory");
    return v;
}
__device__ __forceinline__ void st_u32_l2(unsigned* p, unsigned v) {
    asm volatile("global_store_dword %0, %1, off sc0\n\ts_waitcnt vmcnt(0)"
                 :: "v"(p), "v"(v) : "memory");
}
__device__ __forceinline__ void add_ctr_l2(unsigned* p, unsigned v) {
    asm volatile("global_atomic_add %0, %1, off" :: "v"(p), "v"(v) : "memory");
}
__device__ __forceinline__ void st8_l2(void* p, u64 v) {
    asm volatile("global_store_dwordx2 %0, %1, off sc0\n\ts_waitcnt vmcnt(0)"
                 :: "v"(p), "v"(v) : "memory");
}

__global__ __launch_bounds__(256, 1) void gru_persist(
    const float* __restrict__ xs, const float* __restrict__ w_ih,
    const float* __restrict__ w_hh, const float* __restrict__ b,
    const float* __restrict__ b_n, float* __restrict__ out,
    unsigned* __restrict__ ws, unsigned short* __restrict__ hpub)
{
    const int tid  = threadIdx.x;
    const int wv   = tid >> 6;
    const int lane = tid & 63;
    const int q    = lane >> 4;
    const int c    = lane & 15;
    // ws (u32 idx): ctr[g]@g*16 | ticket[8]@128 | cohort_gid[256]@256 | host_ctr@512 done@513
    //              vctr[g]@576+g*16 | vcnt2[g]@640+g*16 | vbad[g]@704+g*16 | vdat@768+g*8+p
    unsigned* ticket     = ws + 128;
    unsigned* cohort_gid = ws + 256;
    unsigned* host_ctr   = ws + 512;
    unsigned* done       = ws + 513;

    // ---- XCD-placement discovery (agent-scope primitives, proven R2/R3) ----
    __shared__ int sh_gp;
    __shared__ int sh_l2;
    if (tid == 0) {
        int x = (int)(__builtin_amdgcn_s_getreg((7u << 11) | 20u) & 7u); // HW_REG_XCC_ID
        unsigned tk = atomicAdd(&ticket[x], 1u);
        unsigned co = (tk >> 3) & 31u, s = tk & 7u;
        unsigned gv = 0;
        unsigned* gidp = &cohort_gid[(unsigned)x * 32u + co];
        if (s == 7u) {
            unsigned gg = __hip_atomic_fetch_add(host_ctr, 1u, __ATOMIC_RELAXED, __HIP_MEMORY_SCOPE_AGENT);
            gv = gg + 1u;
            __hip_atomic_store(gidp, gv, __ATOMIC_RELEASE, __HIP_MEMORY_SCOPE_AGENT);
            if (gv >= NG) __hip_atomic_store(done, 1u, __ATOMIC_RELEASE, __HIP_MEMORY_SCOPE_AGENT);
        } else {
            for (;;) {
                gv = __hip_atomic_load(gidp, __ATOMIC_ACQUIRE, __HIP_MEMORY_SCOPE_AGENT);
                if (gv) break;
                if (__hip_atomic_load(done, __ATOMIC_ACQUIRE, __HIP_MEMORY_SCOPE_AGENT)) {
                    gv = __hip_atomic_load(gidp, __ATOMIC_ACQUIRE, __HIP_MEMORY_SCOPE_AGENT);
                    break;
                }
                __builtin_amdgcn_s_sleep(8);
            }
        }
        sh_gp = (gv >= 1u && gv <= NG) ? (int)((gv - 1u) * NP + s) : -1;
        sh_l2 = 0;

        // ---- bounded L2-scope handshake: verify sc0 protocol works in-group ----
        if (sh_gp >= 0) {
            int g = sh_gp >> 3, p = sh_gp & 7;
            unsigned* vctr = ws + 576 + g * 16;
            unsigned* vcn2 = ws + 640 + g * 16;
            unsigned* vbad = ws + 704 + g * 16;
            unsigned* vdat = ws + 768 + g * 8;
            unsigned magic = 0xC0DE0000u | ((unsigned)g << 4) | (unsigned)p;
            st_u32_l2(&vdat[p], magic);
            add_ctr_l2(vctr, 1u);
            int ok = 0;
            for (int it = 0; it < (1 << 17); ++it) {
                if (ld_ctr_l2(vctr) >= 8u) { ok = 1; break; }
            }
            if (ok) {
                for (int m = 0; m < 8; ++m)
                    if (ld_ctr_l2(&vdat[m]) != (0xC0DE0000u | ((unsigned)g << 4) | (unsigned)m)) ok = 0;
            }
            // consensus over verdicts (agent scope, proven)
            __hip_atomic_fetch_add(vbad, ok ? 0u : 1u, __ATOMIC_RELAXED, __HIP_MEMORY_SCOPE_AGENT);
            __hip_atomic_fetch_add(vcn2, 1u, __ATOMIC_RELEASE, __HIP_MEMORY_SCOPE_AGENT);
            while (__hip_atomic_load(vcn2, __ATOMIC_ACQUIRE, __HIP_MEMORY_SCOPE_AGENT) < 8u)
                __builtin_amdgcn_s_sleep(2);
            sh_l2 = (__hip_atomic_load(vbad, __ATOMIC_RELAXED, __HIP_MEMORY_SCOPE_AGENT) == 0u);
        }
    }
    __syncthreads();
    const int gp = sh_gp;
    const int l2mode = sh_l2;
    if (gp < 0) return;
    const int g = gp >> 3, p = gp & 7;

    const int hbase = p * HS + wv * 16;
    const int batch = g * 16 + c;
    unsigned* ctrp = ws + g * 16;
    unsigned short* hpub_g = hpub + (size_t)g * 2 * 16 * H_;  // [2][16][H] bf16

    // ---- weight preload ----
    short8 whh[3][16];
    short8 wih[3][8];
#pragma unroll
    for (int gate = 0; gate < 3; ++gate) {
        const float* wr = w_hh + (size_t)(gate * H_ + hbase + c) * H_ + q * 8;
#pragma unroll
        for (int kt = 0; kt < 16; ++kt) whh[gate][kt] = ld8_bf(wr + kt * 32);
        const float* wi = w_ih + (size_t)(gate * H_ + hbase + c) * I_ + q * 8;
#pragma unroll
        for (int kt = 0; kt < 8; ++kt)  wih[gate][kt] = ld8_bf(wi + kt * 32);
    }
    float br[4], bz[4], bni[4], bnn[4];
#pragma unroll
    for (int i = 0; i < 4; ++i) {
        int j = hbase + q * 4 + i;
        br[i]  = b[j];
        bz[i]  = b[H_ + j];
        bni[i] = b[2 * H_ + j];
        bnn[i] = b_n[j];
    }
    float hown[4] = {0.f, 0.f, 0.f, 0.f};

    for (int t = 0; t < T_; ++t) {
        // ---- x GEMM (independent of h; overlaps the wait) ----
        const float* xrow = xs + ((size_t)batch * T_ + t) * I_ + q * 8;
        short8 bx[8];
#pragma unroll
        for (int kt = 0; kt < 8; ++kt) bx[kt] = ld8_bf(xrow + kt * 32);

        floatx4 accr  = {br[0],  br[1],  br[2],  br[3]};
        floatx4 accz  = {bz[0],  bz[1],  bz[2],  bz[3]};
        floatx4 accni = {bni[0], bni[1], bni[2], bni[3]};
        floatx4 accnh = {0.f, 0.f, 0.f, 0.f};
#pragma unroll
        for (int kt = 0; kt < 8; ++kt) {
            accr  = __builtin_amdgcn_mfma_f32_16x16x32_bf16(wih[0][kt], bx[kt], accr,  0, 0, 0);
            accz  = __builtin_amdgcn_mfma_f32_16x16x32_bf16(wih[1][kt], bx[kt], accz,  0, 0, 0);
            accni = __builtin_amdgcn_mfma_f32_16x16x32_bf16(wih[2][kt], bx[kt], accni, 0, 0, 0);
        }

        // ---- wait for h_t (wave-autonomous; every lane polls the group counter) ----
        const unsigned target = 32u * (unsigned)t;
        if (l2mode) {
            while (ld_ctr_l2(ctrp) < target) {}
        } else {
            while (__hip_atomic_load(ctrp, __ATOMIC_RELAXED, __HIP_MEMORY_SCOPE_AGENT) < target)
                __builtin_amdgcn_s_sleep(1);
        }

        // ---- load h_t B-fragments ----
        const unsigned short* hrow = hpub_g + ((size_t)(t & 1) * 16 + c) * H_ + q * 8;
        short8 hb[16];
        if (l2mode) {
            intx4 h0,h1,h2,h3,h4,h5,h6,h7,h8,h9,h10,h11,h12,h13,h14,h15;
            asm volatile(
                "global_load_dwordx4 %0, %16, off sc0\n\t"
                "global_load_dwordx4 %1, %16, off offset:64 sc0\n\t"
                "global_load_dwordx4 %2, %16, off offset:128 sc0\n\t"
                "global_load_dwordx4 %3, %16, off offset:192 sc0\n\t"
                "global_load_dwordx4 %4, %16, off offset:256 sc0\n\t"
                "global_load_dwordx4 %5, %16, off offset:320 sc0\n\t"
                "global_load_dwordx4 %6, %16, off offset:384 sc0\n\t"
                "global_load_dwordx4 %7, %16, off offset:448 sc0\n\t"
                "global_load_dwordx4 %8, %16, off offset:512 sc0\n\t"
                "global_load_dwordx4 %9, %16, off offset:576 sc0\n\t"
                "global_load_dwordx4 %10, %16, off offset:640 sc0\n\t"
                "global_load_dwordx4 %11, %16, off offset:704 sc0\n\t"
                "global_load_dwordx4 %12, %16, off offset:768 sc0\n\t"
                "global_load_dwordx4 %13, %16, off offset:832 sc0\n\t"
                "global_load_dwordx4 %14, %16, off offset:896 sc0\n\t"
                "global_load_dwordx4 %15, %16, off offset:960 sc0\n\t"
                "s_waitcnt vmcnt(0)"
                : "=&v"(h0),"=&v"(h1),"=&v"(h2),"=&v"(h3),
                  "=&v"(h4),"=&v"(h5),"=&v"(h6),"=&v"(h7),
                  "=&v"(h8),"=&v"(h9),"=&v"(h10),"=&v"(h11),
                  "=&v"(h12),"=&v"(h13),"=&v"(h14),"=&v"(h15)
                : "v"(hrow) : "memory");
            hb[0]=as_s8(h0);   hb[1]=as_s8(h1);   hb[2]=as_s8(h2);   hb[3]=as_s8(h3);
            hb[4]=as_s8(h4);   hb[5]=as_s8(h5);   hb[6]=as_s8(h6);   hb[7]=as_s8(h7);
            hb[8]=as_s8(h8);   hb[9]=as_s8(h9);   hb[10]=as_s8(h10); hb[11]=as_s8(h11);
            hb[12]=as_s8(h12); hb[13]=as_s8(h13); hb[14]=as_s8(h14); hb[15]=as_s8(h15);
        } else {
            const u64* hq = (const u64*)hrow;
#pragma unroll
            for (int kt = 0; kt < 16; ++kt) {
                union { u64 u[2]; short8 s; } cv;
                cv.u[0] = __hip_atomic_load(hq + kt * 8,     __ATOMIC_RELAXED, __HIP_MEMORY_SCOPE_AGENT);
                cv.u[1] = __hip_atomic_load(hq + kt * 8 + 1, __ATOMIC_RELAXED, __HIP_MEMORY_SCOPE_AGENT);
                hb[kt] = cv.s;
            }
        }

        // ---- recurrent GEMM ----
#pragma unroll
        for (int kt = 0; kt < 16; ++kt) {
            accr  = __builtin_amdgcn_mfma_f32_16x16x32_bf16(whh[0][kt], hb[kt], accr,  0, 0, 0);
            accz  = __builtin_amdgcn_mfma_f32_16x16x32_bf16(whh[1][kt], hb[kt], accz,  0, 0, 0);
            accnh = __builtin_amdgcn_mfma_f32_16x16x32_bf16(whh[2][kt], hb[kt], accnh, 0, 0, 0);
        }

        // ---- gates ----
#pragma unroll
        for (int i = 0; i < 4; ++i) {
            float r = sigf(accr[i]);
            float z = sigf(accz[i]);
            float n = tanh_(accni[i] + r * (accnh[i] + bnn[i]));
            hown[i] = n + z * (hown[i] - n);
        }

        // ---- publish h_{t+1} slice + bump counter (wave-autonomous) ----
        if (t + 1 < T_) {
            u64 pk = (u64)f2bf(hown[0])
                   | ((u64)f2bf(hown[1]) << 16)
                   | ((u64)f2bf(hown[2]) << 32)
                   | ((u64)f2bf(hown[3]) << 48);
            unsigned short* dst = hpub_g + ((size_t)((t + 1) & 1) * 16 + c) * H_ + hbase + q * 4;
            if (l2mode) {
                st8_l2(dst, pk);                       // store + vmcnt(0) ack in L2
                if (lane == 0) add_ctr_l2(ctrp, 1u);
            } else {
                __hip_atomic_store((u64*)dst, pk, __ATOMIC_RELAXED, __HIP_MEMORY_SCOPE_AGENT);
                asm volatile("s_waitcnt vmcnt(0)" ::: "memory");
                if (lane == 0)
                    __hip_atomic_fetch_add(ctrp, 1u, __ATOMIC_RELAXED, __HIP_MEMORY_SCOPE_AGENT);
            }
        }
    }

    floatx4 o = {hown[0], hown[1], hown[2], hown[3]};
    *(floatx4*)(out + (size_t)batch * H_ + hbase + q * 4) = o;
}

extern "C" void kernel_launch(void* const* d_in, const int* in_sizes, int n_in,
                              void* d_out, int out_size, void* d_ws, size_t ws_size,
                              hipStream_t stream) {
    (void)in_sizes; (void)n_in; (void)out_size; (void)ws_size;
    const float* xs   = (const float*)d_in[0];
    const float* w_ih = (const float*)d_in[1];
    const float* w_hh = (const float*)d_in[2];
    const float* b    = (const float*)d_in[3];
    const float* b_n  = (const float*)d_in[4];
    float* out = (float*)d_out;

    unsigned*       ws   = (unsigned*)d_ws;
    unsigned short* hpub = (unsigned short*)((char*)d_ws + 4096);  // 4 x [2][16][512] bf16 = 128KB

    (void)hipMemsetAsync(d_ws, 0, 4096 + (size_t)NG * 2 * 16 * H_ * sizeof(unsigned short), stream);

    gru_persist<<<NBLK, 256, 0, stream>>>(xs, w_ih, w_hh, b, b_n, out, ws, hpub);
}